// Round 10
// baseline (132.435 us; speedup 1.0000x reference)
//
#include <hip/hip_runtime.h>

#define BB 4
#define TT 4096
#define CC 1024
#define HH 64
#define AW 8   // attn key-split waves per block

// O^T publish stride (floats): 35 -> write <=3-way banks, merge read exact 2-way (free).
// Per-warp shbuf row 2276 floats: 2276*4 % 16 == 0 keeps P-region b128 reads 16B-aligned.
#define OS 35
#define LSB (64 * OS)     // lsum base: 2240
#define SHROW 2276

typedef unsigned short us;
typedef us v8u __attribute__((ext_vector_type(8)));
typedef us v4u __attribute__((ext_vector_type(4)));
typedef __bf16 v8bf __attribute__((ext_vector_type(8)));
typedef float v4f __attribute__((ext_vector_type(4)));

// native RNE f32->bf16 (lowers to v_cvt_pk_bf16_f32; 1 instr vs 4-5 VALU bit-trick)
__device__ __forceinline__ us f2bf(float f) {
  return __builtin_bit_cast(us, (__bf16)f);
}
__device__ __forceinline__ v8bf ldb(const us* p) {
  return __builtin_bit_cast(v8bf, *(const v8u*)p);
}

// ---- convert weights fp32 -> fragment-packed bf16: wpack[t][oc][kc][lane][8] ----
__global__ __launch_bounds__(256) void convertw_kernel(const float* __restrict__ Wk,
                                                       const float* __restrict__ Wq,
                                                       const float* __restrict__ Wv,
                                                       us* __restrict__ wpack) {
  const int g = blockIdx.x * 256 + threadIdx.x;   // [0, 3*4*32*64)
  const int t = g >> 13;
  const int rem = g & 8191;
  const int oc = rem >> 11;
  const int kc = (rem >> 6) & 31;
  const int lane = rem & 63;
  const float* W = (t == 0) ? Wq : ((t == 1) ? Wk : Wv);
  const int h  = oc * 16 + (lane & 15);
  const int d0 = kc * 32 + (lane >> 4) * 8;
  const float4* src = (const float4*)(W + h * CC + d0);
  const float4 f0 = src[0], f1 = src[1];
  v8u o;
  o[0]=f2bf(f0.x); o[1]=f2bf(f0.y); o[2]=f2bf(f0.z); o[3]=f2bf(f0.w);
  o[4]=f2bf(f1.x); o[5]=f2bf(f1.y); o[6]=f2bf(f1.z); o[7]=f2bf(f1.w);
  *(v8u*)(wpack + (size_t)g * 8) = o;
}

// Packed activation layouts (bf16):
//  qpack/kpack: [b][tile32][half][dhalf][lane][8]; vpack: [b][tile32][oc][lane][8]

// ---------------- Projection v9: intra-block stage/compute pipeline --------------------------
// Co-resident blocks are phase-locked (launch together): both stage (MFMA idle) then both
// compute (HBM idle). Fix inside the block: stage rows 0-15 -> barrier -> ISSUE rows 16-31
// global loads to registers -> compute rg0 (HBM stream hides under 32-kc MFMA loop) ->
// write rows 16-31 -> barrier -> compute rg1. Weight loads run twice (L2-hit, cheap).
__global__ __launch_bounds__(768, 6) void proj_kernel(
    const float* __restrict__ x, const us* __restrict__ wpack,
    us* __restrict__ qpack, us* __restrict__ kpack, us* __restrict__ vpack)
{
  __shared__ __align__(16) us xlds[2][16][1048];  // 67,072 B (same total as v8)

  const int tid  = threadIdx.x;
  const int lane = tid & 63, w = tid >> 6;
  const int i16 = lane & 15, quad = lane >> 4;
  const int t = w >> 2, oc = w & 3;             // wave -> (tensor, oc) panel
  const int rows0 = blockIdx.x * 32;

  const float4* xg4 = (const float4*)(x + (size_t)rows0 * CC);

  // ---- phase A: stage rows 0-15 (4096 float4) into xlds[0], coalesced ----
  #pragma unroll
  for (int j = 0; j < 6; j++) {
    const int i = tid + j * 768;
    if (i < 4096) {
      const float4 f = xg4[i];
      v4u o; o[0]=f2bf(f.x); o[1]=f2bf(f.y); o[2]=f2bf(f.z); o[3]=f2bf(f.w);
      *(v4u*)&xlds[0][i >> 8][(i & 255) * 4] = o;
    }
  }
  __syncthreads();

  // ---- phase B: issue rows 16-31 loads to registers (stream under compute rg0) ----
  float4 fB[6];
  #pragma unroll
  for (int j = 0; j < 6; j++) {
    const int i = tid + j * 768;
    if (i < 4096) fB[j] = xg4[4096 + i];
  }

  const us* wp = wpack + (size_t)w * 16384 + lane * 8;   // w == t*4+oc
  v4f zero = {0.f, 0.f, 0.f, 0.f};
  v4f acc[2] = {zero, zero};

  // ---- compute rg0 on xlds[0]: 32 kc x (1 weight load + 1 ds_read_b128 + 1 MFMA) ----
  #pragma unroll 4
  for (int kc = 0; kc < 32; kc++) {
    const v8bf wf = ldb(wp + kc * 512);
    const v8bf a = ldb(&xlds[0][i16][kc * 32 + quad * 8]);
    acc[0] = __builtin_amdgcn_mfma_f32_16x16x32_bf16(a, wf, acc[0], 0, 0, 0);
  }

  // ---- write rows 16-31 into xlds[1] ----
  #pragma unroll
  for (int j = 0; j < 6; j++) {
    const int i = tid + j * 768;
    if (i < 4096) {
      v4u o; o[0]=f2bf(fB[j].x); o[1]=f2bf(fB[j].y); o[2]=f2bf(fB[j].z); o[3]=f2bf(fB[j].w);
      *(v4u*)&xlds[1][i >> 8][(i & 255) * 4] = o;
    }
  }
  __syncthreads();

  // ---- compute rg1 on xlds[1] ----
  #pragma unroll 4
  for (int kc = 0; kc < 32; kc++) {
    const v8bf wf = ldb(wp + kc * 512);
    const v8bf a = ldb(&xlds[1][i16][kc * 32 + quad * 8]);
    acc[1] = __builtin_amdgcn_mfma_f32_16x16x32_bf16(a, wf, acc[1], 0, 0, 0);
  }

  // ---- epilogue: pack stores (layouts identical to v8) ----
  const float COEF = 0.015625f * 1.4426950408889634f;  // scale^2 * log2(e), folded into q
  const int b    = rows0 >> 12;
  const int tile = (rows0 & (TT - 1)) >> 5;

  if (t < 2) {
    us* dst = t ? kpack : qpack;
    const float c = t ? 1.0f : COEF;
    const int h = oc * 16 + i16;
    #pragma unroll
    for (int rg = 0; rg < 2; rg++) {
      #pragma unroll
      for (int r = 0; r < 4; r++) {
        const int tr = quad * 4 + r;
        const int lane2 = tr + 16 * ((h >> 3) & 3);
        const size_t idx = ((((size_t)(b * 128 + tile) * 2 + rg) * 2 + (h >> 5)) * 64 + lane2) * 8 + (h & 7);
        dst[idx] = f2bf(acc[rg][r] * c);
      }
    }
  } else {
    #pragma unroll
    for (int rg = 0; rg < 2; rg++) {
      const int lane3 = i16 + 16 * (rg * 2 + (quad >> 1));
      v4u pk;
      #pragma unroll
      for (int r = 0; r < 4; r++) pk[r] = f2bf(acc[rg][r]);
      *(v4u*)&vpack[(((size_t)(b * 128 + tile) * 4 + oc) * 64 + lane3) * 8 + (quad & 1) * 4] = pk;
    }
  }
}

// ---------------- Flash attention v8b: r9 structure + s_setprio around MFMA clusters --------
__global__ __launch_bounds__(512, 4) void attn_kernel(
    const us* __restrict__ qpack, const us* __restrict__ kpack,
    const us* __restrict__ vpack, float* __restrict__ out)
{
  // per-wave SHROW=2276 floats: loop uses first 1280 (P dbuf us[2][2][16][40], 16B-aligned);
  // after loop: O^T [64][OS=35] at 0 + lsum[32] at LSB=2240. 72.8 KB total, 2 blocks/CU.
  __shared__ float shbuf[AW][SHROW];

  const int tid  = threadIdx.x;
  const int lane = tid & 63, warp = tid >> 6;
  const int i16 = lane & 15, quad = lane >> 4;

  // pairing: blocks p and p+256 land on the same CU with complementary key-range lengths;
  // i%8 = b + 4*(q0&1): each XCD pair {b, b+4} serves one batch b (K/V_b ~1MB fits its L2)
  const int p = blockIdx.x & 255, s = blockIdx.x >> 8;
  const int b  = p & 3;
  const int q0 = p >> 2;
  const int qb = s ? (127 - q0) : q0;
  const int i0 = qb << 5;
  const int nt = min(qb + 2, 128);

  us* Pw = (us*)shbuf[warp];
  const float NEGINF = -__builtin_inff();

  v8bf qf[2][2];
  #pragma unroll
  for (int ih = 0; ih < 2; ih++)
    #pragma unroll
    for (int g = 0; g < 2; g++)
      qf[ih][g] = ldb(qpack + ((((size_t)(b * 128 + qb) * 2 + ih) * 2 + g) * 64 + lane) * 8);

  v4f zero = {0.f, 0.f, 0.f, 0.f};
  v4f oacc[2][4];
  #pragma unroll
  for (int ih = 0; ih < 2; ih++)
    #pragma unroll
    for (int oc = 0; oc < 4; oc++) oacc[ih][oc] = zero;
  float lsum[2] = {0.f, 0.f};

  auto loadK = [&](int t, v8bf kf[2][2]) {
    #pragma unroll
    for (int f = 0; f < 2; f++)
      #pragma unroll
      for (int g = 0; g < 2; g++)
        kf[f][g] = ldb(kpack + ((((size_t)(b * 128 + t) * 2 + f) * 2 + g) * 64 + lane) * 8);
  };
  auto loadV = [&](int t, v8bf vf[4]) {
    #pragma unroll
    for (int oc = 0; oc < 4; oc++)
      vf[oc] = ldb(vpack + (((size_t)(b * 128 + t) * 4 + oc) * 64 + lane) * 8);
  };
  auto qk_exp_store = [&](int t, const v8bf kf[2][2], int buf) {
    v4f sacc[2][2];
    __builtin_amdgcn_s_setprio(1);
    #pragma unroll
    for (int ih = 0; ih < 2; ih++)
      #pragma unroll
      for (int f = 0; f < 2; f++) {
        v4f sv = zero;
        sv = __builtin_amdgcn_mfma_f32_16x16x32_bf16(kf[f][0], qf[ih][0], sv, 0, 0, 0);
        sv = __builtin_amdgcn_mfma_f32_16x16x32_bf16(kf[f][1], qf[ih][1], sv, 0, 0, 0);
        sacc[ih][f] = sv;
      }
    __builtin_amdgcn_s_setprio(0);
    const int j0 = t * 32;
    const bool needMask = (t >= qb);
    #pragma unroll
    for (int ih = 0; ih < 2; ih++) {
      float ps[8];
      #pragma unroll
      for (int f = 0; f < 2; f++)
        #pragma unroll
        for (int r = 0; r < 4; r++) {
          float sv = fminf(sacc[ih][f][r], 80.f);
          if (needMask) {
            const int j = j0 + f * 16 + quad * 4 + r;
            const int i = i0 + ih * 16 + i16;
            sv = (j <= i + 1) ? sv : NEGINF;
          }
          ps[f * 4 + r] = exp2f(sv);
        }
      // tree-sum: shorter dep chain than 8 serial adds (and more accurate)
      {
        const float s0 = ps[0] + ps[1], s1 = ps[2] + ps[3];
        const float s2 = ps[4] + ps[5], s3 = ps[6] + ps[7];
        lsum[ih] += (s0 + s1) + (s2 + s3);
      }
      #pragma unroll
      for (int f = 0; f < 2; f++) {
        v4u pk;
        #pragma unroll
        for (int r = 0; r < 4; r++) pk[r] = f2bf(ps[f * 4 + r]);
        *(v4u*)&Pw[buf * 1280 + ih * 640 + i16 * 40 + f * 16 + quad * 4] = pk;
      }
    }
  };
  auto pv = [&](int buf, const v8bf vf[4]) {
    __builtin_amdgcn_s_setprio(1);
    #pragma unroll
    for (int ih = 0; ih < 2; ih++) {
      v8bf pf = __builtin_bit_cast(v8bf, *(const v8u*)&Pw[buf * 1280 + ih * 640 + i16 * 40 + quad * 8]);
      #pragma unroll
      for (int oc = 0; oc < 4; oc++)
        oacc[ih][oc] = __builtin_amdgcn_mfma_f32_16x16x32_bf16(vf[oc], pf, oacc[ih][oc], 0, 0, 0);
    }
    __builtin_amdgcn_s_setprio(0);
  };

  // software pipeline (register-lean):
  //   P double-buffer: pv(t-AW) consumes P stored one iteration earlier
  //   K: kcur/knxt rotate, loaded one full iteration before qk
  //   V: loaded right after pv frees the single V buffer, consumed next iteration
  int t = warp, buf = 0;
  if (t < nt) {
    v8bf kcur[2][2], knxt[2][2], vprev[4];
    loadK(t, kcur); loadV(t, vprev);
    if (t + AW < nt) loadK(t + AW, knxt);
    qk_exp_store(t, kcur, 0);        // first tile: load exposure unavoidable
    #pragma unroll 2
    for (t += AW; t < nt; t += AW) {
      pv(buf, vprev);                // O += P(t-AW)*V(t-AW); vprev now dead
      loadV(t, vprev);               // V(t) -> consumed next iteration
      #pragma unroll
      for (int f = 0; f < 2; f++)
        #pragma unroll
        for (int g = 0; g < 2; g++) kcur[f][g] = knxt[f][g];
      if (t + AW < nt) loadK(t + AW, knxt);
      qk_exp_store(t, kcur, buf ^ 1);  // K(t) was loaded last iteration
      buf ^= 1;
    }
    pv(buf, vprev);                  // drain: P(t_last)*V(t_last)
  }

  // publish per-wave partials (stride OS=35: write <=3-way, merge read 2-way free)
  #pragma unroll
  for (int ih = 0; ih < 2; ih++) {
    lsum[ih] += __shfl_xor(lsum[ih], 16, 64);
    lsum[ih] += __shfl_xor(lsum[ih], 32, 64);
    #pragma unroll
    for (int oc = 0; oc < 4; oc++)
      #pragma unroll
      for (int r = 0; r < 4; r++)
        shbuf[warp][(oc * 16 + quad * 4 + r) * OS + ih * 16 + i16] = oacc[ih][oc][r];
  }
  if (lane < 16) {
    shbuf[warp][LSB + lane]      = lsum[0];
    shbuf[warp][LSB + 16 + lane] = lsum[1];
  }
  __syncthreads();

  // merge AW=8 key-split waves; thread (iw, o) handles rows i = iw + 8*rr
  const int o  = tid & 63;
  const int iw = tid >> 6;
  #pragma unroll
  for (int rr = 0; rr < 4; rr++) {
    const int i = iw + rr * 8;
    float L = 0.f, O = 0.f;
    #pragma unroll
    for (int w = 0; w < AW; w++) {
      L += shbuf[w][LSB + i];
      O += shbuf[w][o * OS + i];
    }
    out[(size_t)(b * TT + i0 + i) * HH + o] = O / L;
  }
}

extern "C" void kernel_launch(void* const* d_in, const int* in_sizes, int n_in,
                              void* d_out, int out_size, void* d_ws, size_t ws_size,
                              hipStream_t stream) {
  const size_t NWP = 3 * 4 * 32 * 64 * 8;      // 196,608 elems wpack
  const size_t NP  = (size_t)BB * TT * HH;     // 4,194,304 elems per pack

  us* wpack = (us*)d_ws;
  us* qpack = wpack + NWP;
  us* kpack = qpack + NP;
  us* vpack = kpack + NP;                      // total ws ~25.5 MB
  float* out = (float*)d_out;

  convertw_kernel<<<96, 256, 0, stream>>>(
      (const float*)d_in[1], (const float*)d_in[2], (const float*)d_in[3], wpack);
  proj_kernel<<<BB * TT / 32, 768, 0, stream>>>(
      (const float*)d_in[0], wpack, qpack, kpack, vpack);
  attn_kernel<<<512, 512, 0, stream>>>(qpack, kpack, vpack, out);
}

// Round 11
// 129.149 us; speedup vs baseline: 1.0254x; 1.0254x over previous
//
#include <hip/hip_runtime.h>

#define BB 4
#define TT 4096
#define CC 1024
#define HH 64
#define AW 8   // attn key-split waves per block

typedef unsigned short us;
typedef us v8u __attribute__((ext_vector_type(8)));
typedef us v4u __attribute__((ext_vector_type(4)));
typedef __bf16 v8bf __attribute__((ext_vector_type(8)));
typedef float v4f __attribute__((ext_vector_type(4)));

// native RNE f32->bf16 (lowers to v_cvt_pk_bf16_f32; 1 instr vs 4-5 VALU bit-trick)
__device__ __forceinline__ us f2bf(float f) {
  return __builtin_bit_cast(us, (__bf16)f);
}
__device__ __forceinline__ v8bf ldb(const us* p) {
  return __builtin_bit_cast(v8bf, *(const v8u*)p);
}

// ---- convert weights fp32 -> fragment-packed bf16: wpack[t][oc][kc][lane][8] ----
__global__ __launch_bounds__(256) void convertw_kernel(const float* __restrict__ Wk,
                                                       const float* __restrict__ Wq,
                                                       const float* __restrict__ Wv,
                                                       us* __restrict__ wpack) {
  const int g = blockIdx.x * 256 + threadIdx.x;   // [0, 3*4*32*64)
  const int t = g >> 13;
  const int rem = g & 8191;
  const int oc = rem >> 11;
  const int kc = (rem >> 6) & 31;
  const int lane = rem & 63;
  const float* W = (t == 0) ? Wq : ((t == 1) ? Wk : Wv);
  const int h  = oc * 16 + (lane & 15);
  const int d0 = kc * 32 + (lane >> 4) * 8;
  const float4* src = (const float4*)(W + h * CC + d0);
  const float4 f0 = src[0], f1 = src[1];
  v8u o;
  o[0]=f2bf(f0.x); o[1]=f2bf(f0.y); o[2]=f2bf(f0.z); o[3]=f2bf(f0.w);
  o[4]=f2bf(f1.x); o[5]=f2bf(f1.y); o[6]=f2bf(f1.z); o[7]=f2bf(f1.w);
  *(v8u*)(wpack + (size_t)g * 8) = o;
}

// Packed activation layouts (bf16):
//  qpack/kpack: [b][tile32][half][dhalf][lane][8]; vpack: [b][tile32][oc][lane][8]

// ---------------- Projection v8: 32-row blocks, 2 resident/CU, single-pass stage ------------
__global__ __launch_bounds__(768, 6) void proj_kernel(
    const float* __restrict__ x, const us* __restrict__ wpack,
    us* __restrict__ qpack, us* __restrict__ kpack, us* __restrict__ vpack)
{
  __shared__ __align__(16) us xlds[32][1048];   // 67,072 B

  const int tid  = threadIdx.x;
  const int lane = tid & 63, w = tid >> 6;
  const int i16 = lane & 15, quad = lane >> 4;
  const int t = w >> 2, oc = w & 3;             // wave -> (tensor, oc) panel
  const int rows0 = blockIdx.x * 32;

  // ---- stage 32 x 1024 fp32 -> bf16 LDS once, fully coalesced (256 f4 per row) ----
  const float4* xg4 = (const float4*)(x + (size_t)rows0 * CC);
  for (int i = tid; i < 8192; i += 768) {
    const float4 f = xg4[i];
    v4u o; o[0]=f2bf(f.x); o[1]=f2bf(f.y); o[2]=f2bf(f.z); o[3]=f2bf(f.w);
    *(v4u*)&xlds[i >> 8][(i & 255) * 4] = o;
  }
  __syncthreads();

  // ---- full-K, barrier-free: 32 kc x (1 weight load + 2 ds_read_b128 + 2 MFMA) ----
  const us* wp = wpack + (size_t)w * 16384 + lane * 8;   // w == t*4+oc
  v4f zero = {0.f, 0.f, 0.f, 0.f};
  v4f acc[2] = {zero, zero};

  #pragma unroll 4
  for (int kc = 0; kc < 32; kc++) {
    const v8bf wf = ldb(wp + kc * 512);
    #pragma unroll
    for (int rg = 0; rg < 2; rg++) {
      const v8bf a = ldb(&xlds[rg * 16 + i16][kc * 32 + quad * 8]);
      acc[rg] = __builtin_amdgcn_mfma_f32_16x16x32_bf16(a, wf, acc[rg], 0, 0, 0);
    }
  }

  // ---- epilogue: pack stores (layouts identical to v7b, collapsed to one tile) ----
  const float COEF = 0.015625f * 1.4426950408889634f;  // scale^2 * log2(e), folded into q
  const int b    = rows0 >> 12;
  const int tile = (rows0 & (TT - 1)) >> 5;

  if (t < 2) {
    us* dst = t ? kpack : qpack;
    const float c = t ? 1.0f : COEF;
    const int h = oc * 16 + i16;
    #pragma unroll
    for (int rg = 0; rg < 2; rg++) {
      #pragma unroll
      for (int r = 0; r < 4; r++) {
        const int tr = quad * 4 + r;
        const int lane2 = tr + 16 * ((h >> 3) & 3);
        const size_t idx = ((((size_t)(b * 128 + tile) * 2 + rg) * 2 + (h >> 5)) * 64 + lane2) * 8 + (h & 7);
        dst[idx] = f2bf(acc[rg][r] * c);
      }
    }
  } else {
    #pragma unroll
    for (int rg = 0; rg < 2; rg++) {
      const int lane3 = i16 + 16 * (rg * 2 + (quad >> 1));
      v4u pk;
      #pragma unroll
      for (int r = 0; r < 4; r++) pk[r] = f2bf(acc[rg][r]);
      *(v4u*)&vpack[(((size_t)(b * 128 + tile) * 4 + oc) * 64 + lane3) * 8 + (quad & 1) * 4] = pk;
    }
  }
}

// ---------------- Flash attention v6: 8-wave key-split, 128-VGPR cap -> 2 blocks/CU ----------
// v5 used ~170 VGPR -> 1 block/CU: short/long pairing broken (shorts all retire first),
// long blocks ran 16 serial iters at 2 waves/SIMD. v6 caps at 128 VGPR (launch_bounds 512,4)
// with a slimmer pipeline: K prefetched one iter ahead (kcur/knxt rotate); V(t) loaded into
// the slot freed by pv() and consumed one iteration later (single V buffer, -16 VGPR).
__global__ __launch_bounds__(512, 4) void attn_kernel(
    const us* __restrict__ qpack, const us* __restrict__ kpack,
    const us* __restrict__ vpack, float* __restrict__ out)
{
  // per-wave 2148 floats: loop uses first 1280 (P dbuf us[2][2][16][40]);
  // after loop: O^T [64][33] + lsum[32] at 2112. Total 68,736 B (2 blocks = 137 KB <= 160).
  __shared__ float shbuf[AW][2148];

  const int tid  = threadIdx.x;
  const int lane = tid & 63, warp = tid >> 6;
  const int i16 = lane & 15, quad = lane >> 4;

  // pairing: blocks p and p+256 land on the same CU (same XCD, slots 0/1) with
  // complementary key-range lengths -> balanced per-CU work when 2 blocks co-reside
  const int p = blockIdx.x & 255, s = blockIdx.x >> 8;
  const int b  = p & 3;
  const int q0 = p >> 2;
  const int qb = s ? (127 - q0) : q0;
  const int i0 = qb << 5;
  const int nt = min(qb + 2, 128);

  us* Pw = (us*)shbuf[warp];
  const float NEGINF = -__builtin_inff();

  v8bf qf[2][2];
  #pragma unroll
  for (int ih = 0; ih < 2; ih++)
    #pragma unroll
    for (int g = 0; g < 2; g++)
      qf[ih][g] = ldb(qpack + ((((size_t)(b * 128 + qb) * 2 + ih) * 2 + g) * 64 + lane) * 8);

  v4f zero = {0.f, 0.f, 0.f, 0.f};
  v4f oacc[2][4];
  #pragma unroll
  for (int ih = 0; ih < 2; ih++)
    #pragma unroll
    for (int oc = 0; oc < 4; oc++) oacc[ih][oc] = zero;
  float lsum[2] = {0.f, 0.f};

  auto loadK = [&](int t, v8bf kf[2][2]) {
    #pragma unroll
    for (int f = 0; f < 2; f++)
      #pragma unroll
      for (int g = 0; g < 2; g++)
        kf[f][g] = ldb(kpack + ((((size_t)(b * 128 + t) * 2 + f) * 2 + g) * 64 + lane) * 8);
  };
  auto loadV = [&](int t, v8bf vf[4]) {
    #pragma unroll
    for (int oc = 0; oc < 4; oc++)
      vf[oc] = ldb(vpack + (((size_t)(b * 128 + t) * 4 + oc) * 64 + lane) * 8);
  };
  auto qk_exp_store = [&](int t, const v8bf kf[2][2], int buf) {
    v4f sacc[2][2];
    #pragma unroll
    for (int ih = 0; ih < 2; ih++)
      #pragma unroll
      for (int f = 0; f < 2; f++) {
        v4f sv = zero;
        sv = __builtin_amdgcn_mfma_f32_16x16x32_bf16(kf[f][0], qf[ih][0], sv, 0, 0, 0);
        sv = __builtin_amdgcn_mfma_f32_16x16x32_bf16(kf[f][1], qf[ih][1], sv, 0, 0, 0);
        sacc[ih][f] = sv;
      }
    const int j0 = t * 32;
    const bool needMask = (t >= qb);
    #pragma unroll
    for (int ih = 0; ih < 2; ih++) {
      float ps[8];
      #pragma unroll
      for (int f = 0; f < 2; f++)
        #pragma unroll
        for (int r = 0; r < 4; r++) {
          float sv = fminf(sacc[ih][f][r], 80.f);
          if (needMask) {
            const int j = j0 + f * 16 + quad * 4 + r;
            const int i = i0 + ih * 16 + i16;
            sv = (j <= i + 1) ? sv : NEGINF;
          }
          ps[f * 4 + r] = exp2f(sv);
        }
      // tree-sum: shorter dep chain than 8 serial adds (and more accurate)
      {
        const float s0 = ps[0] + ps[1], s1 = ps[2] + ps[3];
        const float s2 = ps[4] + ps[5], s3 = ps[6] + ps[7];
        lsum[ih] += (s0 + s1) + (s2 + s3);
      }
      #pragma unroll
      for (int f = 0; f < 2; f++) {
        v4u pk;
        #pragma unroll
        for (int r = 0; r < 4; r++) pk[r] = f2bf(ps[f * 4 + r]);
        *(v4u*)&Pw[buf * 1280 + ih * 640 + i16 * 40 + f * 16 + quad * 4] = pk;
      }
    }
  };
  auto pv = [&](int buf, const v8bf vf[4]) {
    #pragma unroll
    for (int ih = 0; ih < 2; ih++) {
      v8bf pf = __builtin_bit_cast(v8bf, *(const v8u*)&Pw[buf * 1280 + ih * 640 + i16 * 40 + quad * 8]);
      #pragma unroll
      for (int oc = 0; oc < 4; oc++)
        oacc[ih][oc] = __builtin_amdgcn_mfma_f32_16x16x32_bf16(vf[oc], pf, oacc[ih][oc], 0, 0, 0);
    }
  };

  // software pipeline (register-lean):
  //   P double-buffer: pv(t-AW) consumes P stored one iteration earlier
  //   K: kcur/knxt rotate, loaded one full iteration before qk
  //   V: loaded right after pv frees the single V buffer, consumed next iteration
  int t = warp, buf = 0;
  if (t < nt) {
    v8bf kcur[2][2], knxt[2][2], vprev[4];
    loadK(t, kcur); loadV(t, vprev);
    if (t + AW < nt) loadK(t + AW, knxt);
    qk_exp_store(t, kcur, 0);        // first tile: load exposure unavoidable
    #pragma unroll 2
    for (t += AW; t < nt; t += AW) {
      pv(buf, vprev);                // O += P(t-AW)*V(t-AW); vprev now dead
      loadV(t, vprev);               // V(t) -> consumed next iteration
      #pragma unroll
      for (int f = 0; f < 2; f++)
        #pragma unroll
        for (int g = 0; g < 2; g++) kcur[f][g] = knxt[f][g];
      if (t + AW < nt) loadK(t + AW, knxt);
      qk_exp_store(t, kcur, buf ^ 1);  // K(t) was loaded last iteration
      buf ^= 1;
    }
    pv(buf, vprev);                  // drain: P(t_last)*V(t_last)
  }

  // publish per-wave partials
  #pragma unroll
  for (int ih = 0; ih < 2; ih++) {
    lsum[ih] += __shfl_xor(lsum[ih], 16, 64);
    lsum[ih] += __shfl_xor(lsum[ih], 32, 64);
    #pragma unroll
    for (int oc = 0; oc < 4; oc++)
      #pragma unroll
      for (int r = 0; r < 4; r++)
        shbuf[warp][(oc * 16 + quad * 4 + r) * 33 + ih * 16 + i16] = oacc[ih][oc][r];
  }
  if (lane < 16) {
    shbuf[warp][2112 + lane]      = lsum[0];
    shbuf[warp][2112 + 16 + lane] = lsum[1];
  }
  __syncthreads();

  // merge AW=8 key-split waves; thread (iw, o) handles rows i = iw + 8*rr
  const int o  = tid & 63;
  const int iw = tid >> 6;
  #pragma unroll
  for (int rr = 0; rr < 4; rr++) {
    const int i = iw + rr * 8;
    float L = 0.f, O = 0.f;
    #pragma unroll
    for (int w = 0; w < AW; w++) {
      L += shbuf[w][2112 + i];
      O += shbuf[w][o * 33 + i];
    }
    out[(size_t)(b * TT + i0 + i) * HH + o] = O / L;
  }
}

extern "C" void kernel_launch(void* const* d_in, const int* in_sizes, int n_in,
                              void* d_out, int out_size, void* d_ws, size_t ws_size,
                              hipStream_t stream) {
  const size_t NWP = 3 * 4 * 32 * 64 * 8;      // 196,608 elems wpack
  const size_t NP  = (size_t)BB * TT * HH;     // 4,194,304 elems per pack

  us* wpack = (us*)d_ws;
  us* qpack = wpack + NWP;
  us* kpack = qpack + NP;
  us* vpack = kpack + NP;                      // total ws ~25.5 MB
  float* out = (float*)d_out;

  convertw_kernel<<<96, 256, 0, stream>>>(
      (const float*)d_in[1], (const float*)d_in[2], (const float*)d_in[3], wpack);
  proj_kernel<<<BB * TT / 32, 768, 0, stream>>>(
      (const float*)d_in[0], wpack, qpack, kpack, vpack);
  attn_kernel<<<512, 512, 0, stream>>>(qpack, kpack, vpack, out);
}